// Round 1
// baseline (398.430 us; speedup 1.0000x reference)
//
#include <hip/hip_runtime.h>
#include <math.h>

// Problem constants (fixed by reference setup_inputs)
constexpr int BB   = 32;    // batch
constexpr int ZD   = 2048;  // z (feature) dim
constexpr int ND   = 1024;  // W*H
constexpr int ZC   = 32;    // number of z-chunks in pass 1
constexpr int ZPC  = ZD / ZC; // 64 z per chunk

// K1: partial[b][c][n] = sum over z in chunk c of alpha[z] * x[b][z][n]
__global__ __launch_bounds__(256) void k1_partial(const float* __restrict__ x,
                                                  const float* __restrict__ alpha,
                                                  float* __restrict__ partial) {
    const int blk = blockIdx.x;       // b*ZC + c
    const int b   = blk >> 5;         // / ZC
    const int c   = blk & (ZC - 1);
    const int t   = threadIdx.x;      // 0..255 -> n = 4t..4t+3 via float4
    const float4* x4 = (const float4*)x + ((size_t)(b * ZD + c * ZPC) * (ND / 4)) + t;
    float4 acc = make_float4(0.f, 0.f, 0.f, 0.f);
    const float* al = alpha + c * ZPC;
#pragma unroll 8
    for (int z = 0; z < ZPC; ++z) {
        const float a = al[z];                 // wave-uniform -> scalar load
        const float4 v = x4[(size_t)z * (ND / 4)];
        acc.x = fmaf(a, v.x, acc.x);
        acc.y = fmaf(a, v.y, acc.y);
        acc.z = fmaf(a, v.z, acc.z);
        acc.w = fmaf(a, v.w, acc.w);
    }
    ((float4*)partial)[(size_t)blk * (ND / 4) + t] = acc;
}

// K2: h[b][n] = sigmoid(sum_c partial[b][c][n]); denom[b] = sum_n h^2
__global__ __launch_bounds__(1024) void k2_finalize(const float* __restrict__ partial,
                                                    float* __restrict__ h,
                                                    float* __restrict__ denom) {
    const int b = blockIdx.x;
    const int n = threadIdx.x;  // 0..1023
    float s = 0.f;
#pragma unroll
    for (int c = 0; c < ZC; ++c)
        s += partial[((size_t)(b * ZC + c)) * ND + n];
    // numerically-stable sigmoid; expf saturates cleanly for |s| large
    const float hv = 1.0f / (1.0f + expf(-s));
    h[b * ND + n] = hv;

    float d = hv * hv;
#pragma unroll
    for (int o = 32; o > 0; o >>= 1) d += __shfl_down(d, o);  // 64-wide wave
    __shared__ float red[16];
    const int lane = n & 63, w = n >> 6;
    if (lane == 0) red[w] = d;
    __syncthreads();
    if (n == 0) {
        float tot = 0.f;
#pragma unroll
        for (int i = 0; i < 16; ++i) tot += red[i];
        denom[b] = tot;
    }
}

// K3: out[b][z] = (sum_n h[b][n] * x[b][z][n]) / denom[b]
// One block handles 16 z-rows of one b (4 waves x 4 rows each).
__global__ __launch_bounds__(256) void k3_beta(const float* __restrict__ x,
                                               const float* __restrict__ h,
                                               const float* __restrict__ denom,
                                               float* __restrict__ out) {
    __shared__ float4 hs[ND / 4];
    const int blk = blockIdx.x;
    const int b   = blk / (ZD / 16);
    const int zb  = (blk % (ZD / 16)) * 16;
    const int t    = threadIdx.x;
    const int wave = t >> 6;
    const int lane = t & 63;

    hs[t] = ((const float4*)(h + (size_t)b * ND))[t];
    __syncthreads();

    const float dn = denom[b];
#pragma unroll
    for (int r = 0; r < 4; ++r) {
        const int z = zb + wave * 4 + r;
        const float4* row = (const float4*)(x + ((size_t)(b * ZD + z)) * ND);
        float s = 0.f;
#pragma unroll
        for (int k = 0; k < 4; ++k) {
            const float4 v  = row[lane + 64 * k];
            const float4 hv = hs[lane + 64 * k];
            s += v.x * hv.x + v.y * hv.y + v.z * hv.z + v.w * hv.w;
        }
#pragma unroll
        for (int o = 32; o > 0; o >>= 1) s += __shfl_down(s, o);
        if (lane == 0) out[b * ZD + z] = s / dn;
    }
}

extern "C" void kernel_launch(void* const* d_in, const int* in_sizes, int n_in,
                              void* d_out, int out_size, void* d_ws, size_t ws_size,
                              hipStream_t stream) {
    const float* x     = (const float*)d_in[0];
    const float* alpha = (const float*)d_in[1];
    float* out = (float*)d_out;

    // ws layout: partial (B*ZC*ND fp32 = 4 MiB) | h (B*ND fp32 = 128 KiB) | denom (B fp32)
    float* partial = (float*)d_ws;
    float* h       = partial + (size_t)BB * ZC * ND;
    float* denom   = h + (size_t)BB * ND;

    k1_partial<<<BB * ZC, 256, 0, stream>>>(x, alpha, partial);
    k2_finalize<<<BB, 1024, 0, stream>>>(partial, h, denom);
    k3_beta<<<BB * (ZD / 16), 256, 0, stream>>>(x, h, denom, out);
}